// Round 1
// baseline (1124.506 us; speedup 1.0000x reference)
//
#include <hip/hip_runtime.h>
#include <math.h>

// Problem dims (AttentionRNN): B=128, T=64, H=256, V=128
#define BB 128
#define TT 64
#define HH 256
#define G3 768   // 3*H
#define VV 128

// ---------------------------------------------------------------------------
// Pack w_hh [768][256] -> [k/4][768][4] so the GRU inner loop does one
// coalesced float4 load per (k-quad, gate-output) with lane-consecutive gj.
// ---------------------------------------------------------------------------
__global__ __launch_bounds__(256) void pack_whh(const float* __restrict__ w,
                                                float* __restrict__ out) {
    int idx = blockIdx.x * 256 + threadIdx.x;   // 768*256 = 196608 exact
    int gj = idx >> 8;          // /256
    int k  = idx & 255;
    out[((k >> 2) * G3 + gj) * 4 + (k & 3)] = w[idx];
}

// ---------------------------------------------------------------------------
// Generic f32 GEMM: C[M,N] = A[M,K1+K2] @ B[N,K1+K2]^T + bias
// A given as two row-major slabs (A1 for k<K1, A2 for k>=K1) so the final
// logits GEMM can read concat(enc,ctx) without materializing it.
// 64x64 tile, BK=16, 256 threads, 4x4 per thread.  All dims exact multiples.
// ---------------------------------------------------------------------------
__global__ __launch_bounds__(256) void gemm_bt(
    const float* __restrict__ A1, int lda1, int K1,
    const float* __restrict__ A2, int lda2, int K2,
    const float* __restrict__ Bw, int ldb,
    const float* __restrict__ bias,
    float* __restrict__ C, int ldc, int M, int N)
{
    __shared__ alignas(16) float As[16][68];
    __shared__ alignas(16) float Bs[16][68];
    const int tid = threadIdx.x;
    const int lc = tid & 15, lr = tid >> 4;      // load: k-col, row-in-tile
    const int ty = tid >> 4, tx = tid & 15;      // compute: 4x4 block
    const int row0 = blockIdx.y * 64, col0 = blockIdx.x * 64;
    float acc[4][4] = {};
    const int KT = K1 + K2;

    for (int k0 = 0; k0 < KT; k0 += 16) {
        const float* Ap; int lda, kk0;
        if (k0 < K1) { Ap = A1; lda = lda1; kk0 = k0; }
        else         { Ap = A2; lda = lda2; kk0 = k0 - K1; }
#pragma unroll
        for (int r = 0; r < 4; ++r) {
            As[lc][lr + 16 * r] = Ap[(row0 + lr + 16 * r) * lda + kk0 + lc];
            Bs[lc][lr + 16 * r] = Bw[(col0 + lr + 16 * r) * ldb + k0 + lc];
        }
        __syncthreads();
#pragma unroll
        for (int kk = 0; kk < 16; ++kk) {
            const float4 a4 = *(const float4*)&As[kk][ty * 4];
            const float4 b4 = *(const float4*)&Bs[kk][tx * 4];
            const float av[4] = {a4.x, a4.y, a4.z, a4.w};
            const float bv[4] = {b4.x, b4.y, b4.z, b4.w};
#pragma unroll
            for (int i = 0; i < 4; ++i)
#pragma unroll
                for (int j = 0; j < 4; ++j)
                    acc[i][j] += av[i] * bv[j];
        }
        __syncthreads();
    }

    float bv[4];
#pragma unroll
    for (int j = 0; j < 4; ++j)
        bv[j] = bias ? bias[col0 + tx * 4 + j] : 0.f;
#pragma unroll
    for (int i = 0; i < 4; ++i) {
        const int r = row0 + ty * 4 + i;
        float4 o;
        o.x = acc[i][0] + bv[0];
        o.y = acc[i][1] + bv[1];
        o.z = acc[i][2] + bv[2];
        o.w = acc[i][3] + bv[3];
        *(float4*)&C[r * ldc + col0 + tx * 4] = o;
    }
}

// ---------------------------------------------------------------------------
// GRU layer (PyTorch convention), sequential over T inside the kernel.
// 64 blocks x 2 batch rows (recurrence independent per row -> no grid sync).
// 768 threads: thread gj owns gate-output gj for BOTH rows (weights read once).
// mode 0: xp gathered from P0 via token ids.  mode 1: xp read from xp1 buffer.
// ---------------------------------------------------------------------------
__global__ __launch_bounds__(768) void gru_layer(
    const float* __restrict__ wp,     // packed w_hh [64][768][4]
    const float* __restrict__ b_hh,   // [768]
    const float* __restrict__ xsrc,   // P0 [128][768] (mode0) or xp1 [8192][768]
    const int*   __restrict__ xidx,   // token ids (mode0), else unused
    float* __restrict__ out_seq,      // [B*T][256]
    float* __restrict__ hlast,        // [B][256] (written only in mode1, t=63)
    int mode)
{
    __shared__ alignas(16) float h_lds[2][HH];
    __shared__ float hp[2][G3];
    const int tid = threadIdx.x;
    const int r0 = blockIdx.x * 2;

    if (tid < 2 * HH) ((float*)h_lds)[tid] = 0.f;
    __syncthreads();

    const float4* wp4 = (const float4*)wp;      // [64][768]
    const float4* h4  = (const float4*)h_lds;   // [2][64]
    const float bbh = b_hh[tid];

    for (int t = 0; t < TT; ++t) {
        // ---- hp = h @ w_hh.T + b_hh  (each thread: 2 rows x 256-dot) ----
        float acc0 = 0.f, acc1 = 0.f, acc2 = 0.f, acc3 = 0.f;
#pragma unroll 4
        for (int k4 = 0; k4 < 64; k4 += 2) {
            const float4 w0 = wp4[k4 * G3 + tid];
            const float4 w1 = wp4[(k4 + 1) * G3 + tid];
            const float4 ha0 = h4[k4],     hb0 = h4[64 + k4];
            const float4 ha1 = h4[k4 + 1], hb1 = h4[64 + k4 + 1];
            acc0 += w0.x * ha0.x + w0.y * ha0.y + w0.z * ha0.z + w0.w * ha0.w;
            acc1 += w0.x * hb0.x + w0.y * hb0.y + w0.z * hb0.z + w0.w * hb0.w;
            acc2 += w1.x * ha1.x + w1.y * ha1.y + w1.z * ha1.z + w1.w * ha1.w;
            acc3 += w1.x * hb1.x + w1.y * hb1.y + w1.z * hb1.z + w1.w * hb1.w;
        }
        hp[0][tid] = acc0 + acc2 + bbh;
        hp[1][tid] = acc1 + acc3 + bbh;
        __syncthreads();

        // ---- gates + state update (512 threads: 2 rows x 256 units) ----
        if (tid < 2 * HH) {
            const int m = tid >> 8, j = tid & 255;
            const int brow = r0 + m;
            const float* xb = (mode == 0)
                ? (xsrc + xidx[brow * TT + t] * G3)
                : (xsrc + (brow * TT + t) * G3);
            const float xr = xb[j], xz = xb[HH + j], xn = xb[2 * HH + j];
            const float hr = hp[m][j], hz = hp[m][j + HH], hn = hp[m][j + 2 * HH];
            const float rg = 1.f / (1.f + __expf(-(xr + hr)));
            const float zg = 1.f / (1.f + __expf(-(xz + hz)));
            const float ng = tanhf(xn + rg * hn);
            const float hnew = (1.f - zg) * ng + zg * h_lds[m][j];
            h_lds[m][j] = hnew;
            out_seq[(brow * TT + t) * HH + j] = hnew;
            if (mode == 1 && t == TT - 1) hlast[brow * HH + j] = hnew;
        }
        __syncthreads();
    }
}

// ---------------------------------------------------------------------------
// Bahdanau attention, one block per (b,t): energy -> softmax(k) -> ctx.
// tanh(x) = (e^{2x}-1)/(e^{2x}+1); |x| <= 32 guaranteed, so no overflow.
// ---------------------------------------------------------------------------
__device__ __forceinline__ float tanh_fast(float x) {
    const float e = __expf(2.f * x);
    return (e - 1.f) / (e + 1.f);
}

__global__ __launch_bounds__(256) void attn_kernel(
    const float* __restrict__ Wae,   // [B*T][256] keys
    const float* __restrict__ Uah,   // [B*T][256] queries
    const float* __restrict__ enc,   // [B*T][256]
    const float* __restrict__ v_a,   // [256]
    float* __restrict__ ctx)         // [B*T][256]
{
    __shared__ float q[HH], va[HH], sm[TT];
    const int tid = threadIdx.x;
    const int t = blockIdx.x, b = blockIdx.y;

    q[tid]  = Uah[(b * TT + t) * HH + tid];
    va[tid] = v_a[tid];
    __syncthreads();

    const int w = tid >> 6, lane = tid & 63;
#pragma unroll 4
    for (int i = 0; i < 16; ++i) {
        const int k = w * 16 + i;
        const float* we = Wae + (b * TT + k) * HH;
        float s = 0.f;
#pragma unroll
        for (int c = 0; c < 4; ++c) {
            const int h = lane + 64 * c;
            s += va[h] * tanh_fast(we[h] + q[h]);
        }
#pragma unroll
        for (int off = 32; off > 0; off >>= 1) s += __shfl_xor(s, off);
        if (lane == 0) sm[k] = s;
    }
    __syncthreads();

    if (tid < TT) {
        const float e = sm[tid];
        float mx = e;
#pragma unroll
        for (int off = 32; off > 0; off >>= 1) mx = fmaxf(mx, __shfl_xor(mx, off));
        const float p = __expf(e - mx);
        float sum = p;
#pragma unroll
        for (int off = 32; off > 0; off >>= 1) sum += __shfl_xor(sum, off);
        sm[tid] = p / sum;
    }
    __syncthreads();

    float c = 0.f;
    for (int k = 0; k < TT; ++k)
        c += sm[k] * enc[(b * TT + k) * HH + tid];
    ctx[(b * TT + t) * HH + tid] = c;
}

// ---------------------------------------------------------------------------
extern "C" void kernel_launch(void* const* d_in, const int* in_sizes, int n_in,
                              void* d_out, int out_size, void* d_ws, size_t ws_size,
                              hipStream_t stream) {
    const int*   x     = (const int*)  d_in[0];
    const float* embed = (const float*)d_in[1];
    const float* w_ih0 = (const float*)d_in[2];
    const float* w_hh0 = (const float*)d_in[3];
    const float* b_ih0 = (const float*)d_in[4];
    const float* b_hh0 = (const float*)d_in[5];
    const float* w_ih1 = (const float*)d_in[6];
    const float* w_hh1 = (const float*)d_in[7];
    const float* b_ih1 = (const float*)d_in[8];
    const float* b_hh1 = (const float*)d_in[9];
    const float* W_a   = (const float*)d_in[10];
    const float* U_a   = (const float*)d_in[11];
    const float* v_a   = (const float*)d_in[12];
    const float* fc_W  = (const float*)d_in[13];
    const float* fc_b  = (const float*)d_in[14];
    float* out = (float*)d_out;

    // workspace layout (floats)
    float* ws    = (float*)d_ws;
    float* wTp0  = ws;                    // 196608
    float* wTp1  = wTp0 + 196608;         // 196608
    float* P0    = wTp1 + 196608;         // 98304   (embed @ w_ih0.T + b_ih0)
    float* h1    = P0   + 98304;          // 2097152 (layer0 output seq)
    float* xp1   = h1   + 2097152;        // 6291456 (h1 @ w_ih1.T + b_ih1)
    float* enc   = xp1  + 6291456;        // 2097152
    float* Wae   = enc  + 2097152;        // 2097152
    float* Uah   = Wae  + 2097152;        // 2097152
    float* ctxb  = Uah  + 2097152;        // 2097152

    float* logits = out;                  // [8192][128]
    float* hlast  = out + BB * TT * VV;   // [128][256]

    // 1) pack recurrent weights
    pack_whh<<<768, 256, 0, stream>>>(w_hh0, wTp0);
    pack_whh<<<768, 256, 0, stream>>>(w_hh1, wTp1);

    // 2) P0 = embed @ w_ih0.T + b_ih0   (128 x 768, K=256)
    gemm_bt<<<dim3(G3 / 64, VV / 64), 256, 0, stream>>>(
        embed, HH, HH, nullptr, 0, 0, w_ih0, HH, b_ih0, P0, G3, VV, G3);

    // 3) GRU layer 0 (xp gathered from P0 by token id)
    gru_layer<<<BB / 2, G3, 0, stream>>>(wTp0, b_hh0, P0, x, h1, nullptr, 0);

    // 4) xp1 = h1 @ w_ih1.T + b_ih1   (8192 x 768, K=256)
    gemm_bt<<<dim3(G3 / 64, BB * TT / 64), 256, 0, stream>>>(
        h1, HH, HH, nullptr, 0, 0, w_ih1, HH, b_ih1, xp1, G3, BB * TT, G3);

    // 5) GRU layer 1 -> enc, h_last
    gru_layer<<<BB / 2, G3, 0, stream>>>(wTp1, b_hh1, xp1, nullptr, enc, hlast, 1);

    // 6) attention precomputes: Wa_e = enc @ W_a.T ; Ua_h = enc @ U_a.T
    gemm_bt<<<dim3(HH / 64, BB * TT / 64), 256, 0, stream>>>(
        enc, HH, HH, nullptr, 0, 0, W_a, HH, nullptr, Wae, HH, BB * TT, HH);
    gemm_bt<<<dim3(HH / 64, BB * TT / 64), 256, 0, stream>>>(
        enc, HH, HH, nullptr, 0, 0, U_a, HH, nullptr, Uah, HH, BB * TT, HH);

    // 7) attention: energy -> softmax -> ctx
    attn_kernel<<<dim3(TT, BB), 256, 0, stream>>>(Wae, Uah, enc, v_a, ctxb);

    // 8) logits = [enc | ctx] @ fc_W.T + fc_b  (split-A GEMM, K=256+256)
    gemm_bt<<<dim3(VV / 64, BB * TT / 64), 256, 0, stream>>>(
        enc, HH, HH, ctxb, HH, HH, fc_W, 2 * HH, fc_b, logits, VV, BB * TT, VV);
}

// Round 3
// 945.757 us; speedup vs baseline: 1.1890x; 1.1890x over previous
//
#include <hip/hip_runtime.h>
#include <math.h>

// Problem dims (AttentionRNN): B=128, T=64, H=256, V=128
#define BB 128
#define TT 64
#define HH 256
#define G3 768   // 3*H
#define VV 128

typedef _Float16 half8 __attribute__((ext_vector_type(8)));
typedef float f32x4 __attribute__((ext_vector_type(4)));

// ---------------------------------------------------------------------------
// Pack w_hh [768][256] f32 -> f16 MFMA B-fragments, in the exact per-lane
// order gru_mfma consumes: [wave 8][tile 6][ktile 8][lane 64][elem 8].
// Fragment def (v_mfma_f32_16x16x32_f16 B): col = lane&15, k = (lane>>4)*8+e.
// Tile tau: gate g = tau/2, sub s = tau&1 -> ncol = g*256 + wave*32 + s*16.
// ---------------------------------------------------------------------------
__global__ __launch_bounds__(256) void pack_whh_f16(const float* __restrict__ w,
                                                    _Float16* __restrict__ out) {
    int d = blockIdx.x * 256 + threadIdx.x;   // 196608 total
    int e   = d & 7;
    int l   = (d >> 3) & 63;
    int kap = (d >> 9) & 7;
    int wt  = d >> 12;                        // wave*6 + tau
    int wv  = wt / 6, tau = wt % 6;
    int ncol = (tau >> 1) * 256 + wv * 32 + (tau & 1) * 16 + (l & 15);
    int k    = kap * 32 + (l >> 4) * 8 + e;
    out[d] = (_Float16)w[ncol * HH + k];
}

// ---------------------------------------------------------------------------
// Generic f32 GEMM: C[M,N] = A[M,K1+K2] @ B[N,K1+K2]^T + bias
// Split-A so the logits GEMM reads concat(enc,ctx) without materializing it.
// 64x64 tile, BK=16, 256 threads, 4x4 per thread.
// ---------------------------------------------------------------------------
__global__ __launch_bounds__(256) void gemm_bt(
    const float* __restrict__ A1, int lda1, int K1,
    const float* __restrict__ A2, int lda2, int K2,
    const float* __restrict__ Bw, int ldb,
    const float* __restrict__ bias,
    float* __restrict__ C, int ldc, int M, int N)
{
    __shared__ alignas(16) float As[16][68];
    __shared__ alignas(16) float Bs[16][68];
    const int tid = threadIdx.x;
    const int lc = tid & 15, lr = tid >> 4;
    const int ty = tid >> 4, tx = tid & 15;
    const int row0 = blockIdx.y * 64, col0 = blockIdx.x * 64;
    float acc[4][4] = {};
    const int KT = K1 + K2;

    for (int k0 = 0; k0 < KT; k0 += 16) {
        const float* Ap; int lda, kk0;
        if (k0 < K1) { Ap = A1; lda = lda1; kk0 = k0; }
        else         { Ap = A2; lda = lda2; kk0 = k0 - K1; }
#pragma unroll
        for (int r = 0; r < 4; ++r) {
            As[lc][lr + 16 * r] = Ap[(row0 + lr + 16 * r) * lda + kk0 + lc];
            Bs[lc][lr + 16 * r] = Bw[(col0 + lr + 16 * r) * ldb + k0 + lc];
        }
        __syncthreads();
#pragma unroll
        for (int kk = 0; kk < 16; ++kk) {
            const float4 a4 = *(const float4*)&As[kk][ty * 4];
            const float4 b4 = *(const float4*)&Bs[kk][tx * 4];
            const float av[4] = {a4.x, a4.y, a4.z, a4.w};
            const float bv[4] = {b4.x, b4.y, b4.z, b4.w};
#pragma unroll
            for (int i = 0; i < 4; ++i)
#pragma unroll
                for (int j = 0; j < 4; ++j)
                    acc[i][j] += av[i] * bv[j];
        }
        __syncthreads();
    }

    float bv[4];
#pragma unroll
    for (int j = 0; j < 4; ++j)
        bv[j] = bias ? bias[col0 + tx * 4 + j] : 0.f;
#pragma unroll
    for (int i = 0; i < 4; ++i) {
        const int r = row0 + ty * 4 + i;
        float4 o;
        o.x = acc[i][0] + bv[0];
        o.y = acc[i][1] + bv[1];
        o.z = acc[i][2] + bv[2];
        o.w = acc[i][3] + bv[3];
        *(float4*)&C[r * ldc + col0 + tx * 4] = o;
    }
}

// ---------------------------------------------------------------------------
// MFMA GRU layer: 8 blocks x 16 batch rows, 512 threads (8 waves).
// Wave w owns gate-cols [w*32, w*32+32) of each gate (6 N-tiles of 16).
// Per step: hp = h @ w_hh.T via 48 mfma_16x16x32_f16 per wave (K=256),
// then gates in f32, h kept f32 in regs + f16 copy in LDS for next step's A.
// mode 0: xp gathered from P0 by token id.  mode 1: xp read from xp1.
// ---------------------------------------------------------------------------
__global__ __launch_bounds__(512) void gru_mfma(
    const _Float16* __restrict__ wp,  // packed fragments (see pack_whh_f16)
    const float* __restrict__ b_hh,   // [768]
    const float* __restrict__ xsrc,   // P0 [128][768] (mode0) or xp1 [8192][768]
    const int*   __restrict__ xidx,   // token ids (mode0)
    float* __restrict__ out_seq,      // [B*T][256]
    float* __restrict__ hlast,        // [B][256] (mode1 only)
    int mode)
{
    __shared__ alignas(16) _Float16 hbuf[16][264];   // +8 pad: 2-way-free banks
    const int tid = threadIdx.x;
    const int wv = tid >> 6, l = tid & 63;
    const int l15 = l & 15, lhi = l >> 4;
    const int r0 = blockIdx.x * 16;

    for (int i = tid; i < 16 * 264; i += 512) ((_Float16*)hbuf)[i] = (_Float16)0.f;
    __syncthreads();

    int gcol[6]; float bh[6];
#pragma unroll
    for (int tau = 0; tau < 6; ++tau) {
        gcol[tau] = (tau >> 1) * 256 + wv * 32 + (tau & 1) * 16 + l15;
        bh[tau] = b_hh[gcol[tau]];
    }
    float hold[2][4] = {};
    const half8* wp8 = (const half8*)wp;
    const int fb = wv * 6 * 8 * 64;   // wave's fragment base (in half8 units)

    for (int t = 0; t < TT; ++t) {
        // xp gather (issued first; latency hides under the MFMA phase)
        float xv[6][4];
#pragma unroll
        for (int reg = 0; reg < 4; ++reg) {
            const int brow = r0 + lhi * 4 + reg;
            const int base = (mode == 0) ? xidx[brow * TT + t] * G3
                                         : (brow * TT + t) * G3;
#pragma unroll
            for (int tau = 0; tau < 6; ++tau)
                xv[tau][reg] = xsrc[base + gcol[tau]];
        }

        f32x4 acc[6];
#pragma unroll
        for (int tau = 0; tau < 6; ++tau) acc[tau] = (f32x4)0.f;

        // K-loop: 8 k-tiles, 2-deep weight prefetch (register rotation)
        half8 Bf[3][6];
#pragma unroll
        for (int p = 0; p < 2; ++p)
#pragma unroll
            for (int tau = 0; tau < 6; ++tau)
                Bf[p][tau] = wp8[fb + (tau * 8 + p) * 64 + l];
#pragma unroll
        for (int kap = 0; kap < 8; ++kap) {
            if (kap + 2 < 8) {
#pragma unroll
                for (int tau = 0; tau < 6; ++tau)
                    Bf[(kap + 2) % 3][tau] = wp8[fb + (tau * 8 + kap + 2) * 64 + l];
            }
            const half8 a = *(const half8*)&hbuf[l15][kap * 32 + lhi * 8];
#pragma unroll
            for (int tau = 0; tau < 6; ++tau)
                acc[tau] = __builtin_amdgcn_mfma_f32_16x16x32_f16(
                    a, Bf[kap % 3][tau], acc[tau], 0, 0, 0);
        }
        __syncthreads();   // all waves' A-reads done before h is overwritten

        // gates: C-layout col = l&15, row = (l>>4)*4 + reg
#pragma unroll
        for (int s = 0; s < 2; ++s) {
            const int col = wv * 32 + s * 16 + l15;
#pragma unroll
            for (int reg = 0; reg < 4; ++reg) {
                const int row = lhi * 4 + reg;
                const float pr = acc[0 + s][reg] + bh[0 + s] + xv[0 + s][reg];
                const float pz = acc[2 + s][reg] + bh[2 + s] + xv[2 + s][reg];
                const float hn = acc[4 + s][reg] + bh[4 + s];
                const float rg = 1.f / (1.f + __expf(-pr));
                const float zg = 1.f / (1.f + __expf(-pz));
                const float npre = xv[4 + s][reg] + rg * hn;
                const float e2 = __expf(2.f * npre);
                const float ng = (e2 - 1.f) / (e2 + 1.f);
                const float hnew = (1.f - zg) * ng + zg * hold[s][reg];
                hold[s][reg] = hnew;
                hbuf[row][col] = (_Float16)hnew;
                const int brow = r0 + row;
                out_seq[(brow * TT + t) * HH + col] = hnew;
                if (mode == 1 && t == TT - 1) hlast[brow * HH + col] = hnew;
            }
        }
        __syncthreads();
    }
}

// ---------------------------------------------------------------------------
// Bahdanau attention, one block per (b,t): energy -> softmax(k) -> ctx.
// ---------------------------------------------------------------------------
__device__ __forceinline__ float tanh_fast(float x) {
    const float e = __expf(2.f * x);
    return (e - 1.f) / (e + 1.f);
}

__global__ __launch_bounds__(256) void attn_kernel(
    const float* __restrict__ Wae,   // [B*T][256] keys
    const float* __restrict__ Uah,   // [B*T][256] queries
    const float* __restrict__ enc,   // [B*T][256]
    const float* __restrict__ v_a,   // [256]
    float* __restrict__ ctx)         // [B*T][256]
{
    __shared__ float q[HH], va[HH], sm[TT];
    const int tid = threadIdx.x;
    const int t = blockIdx.x, b = blockIdx.y;

    q[tid]  = Uah[(b * TT + t) * HH + tid];
    va[tid] = v_a[tid];
    __syncthreads();

    const int w = tid >> 6, lane = tid & 63;
#pragma unroll 4
    for (int i = 0; i < 16; ++i) {
        const int k = w * 16 + i;
        const float* we = Wae + (b * TT + k) * HH;
        float s = 0.f;
#pragma unroll
        for (int c = 0; c < 4; ++c) {
            const int h = lane + 64 * c;
            s += va[h] * tanh_fast(we[h] + q[h]);
        }
#pragma unroll
        for (int off = 32; off > 0; off >>= 1) s += __shfl_xor(s, off);
        if (lane == 0) sm[k] = s;
    }
    __syncthreads();

    if (tid < TT) {
        const float e = sm[tid];
        float mx = e;
#pragma unroll
        for (int off = 32; off > 0; off >>= 1) mx = fmaxf(mx, __shfl_xor(mx, off));
        const float p = __expf(e - mx);
        float sum = p;
#pragma unroll
        for (int off = 32; off > 0; off >>= 1) sum += __shfl_xor(sum, off);
        sm[tid] = p / sum;
    }
    __syncthreads();

    float c = 0.f;
    for (int k = 0; k < TT; ++k)
        c += sm[k] * enc[(b * TT + k) * HH + tid];
    ctx[(b * TT + t) * HH + tid] = c;
}

// ---------------------------------------------------------------------------
extern "C" void kernel_launch(void* const* d_in, const int* in_sizes, int n_in,
                              void* d_out, int out_size, void* d_ws, size_t ws_size,
                              hipStream_t stream) {
    const int*   x     = (const int*)  d_in[0];
    const float* embed = (const float*)d_in[1];
    const float* w_ih0 = (const float*)d_in[2];
    const float* w_hh0 = (const float*)d_in[3];
    const float* b_ih0 = (const float*)d_in[4];
    const float* b_hh0 = (const float*)d_in[5];
    const float* w_ih1 = (const float*)d_in[6];
    const float* w_hh1 = (const float*)d_in[7];
    const float* b_ih1 = (const float*)d_in[8];
    const float* b_hh1 = (const float*)d_in[9];
    const float* W_a   = (const float*)d_in[10];
    const float* U_a   = (const float*)d_in[11];
    const float* v_a   = (const float*)d_in[12];
    const float* fc_W  = (const float*)d_in[13];
    const float* fc_b  = (const float*)d_in[14];
    float* out = (float*)d_out;

    // workspace layout (float words)
    float* ws = (float*)d_ws;
    _Float16* wT0 = (_Float16*)ws;        // 196608 f16 = 98304 floats
    _Float16* wT1 = wT0 + 196608;         // 196608 f16
    float* P0    = ws   + 196608;         // 98304
    float* h1    = P0   + 98304;          // 2097152
    float* xp1   = h1   + 2097152;        // 6291456
    float* enc   = xp1  + 6291456;        // 2097152
    float* Wae   = enc  + 2097152;        // 2097152
    float* Uah   = Wae  + 2097152;        // 2097152
    float* ctxb  = Uah  + 2097152;        // 2097152

    float* logits = out;                  // [8192][128]
    float* hlast  = out + BB * TT * VV;   // [128][256]

    // 1) pack recurrent weights into f16 MFMA fragments
    pack_whh_f16<<<768, 256, 0, stream>>>(w_hh0, wT0);
    pack_whh_f16<<<768, 256, 0, stream>>>(w_hh1, wT1);

    // 2) P0 = embed @ w_ih0.T + b_ih0   (128 x 768, K=256)
    gemm_bt<<<dim3(G3 / 64, VV / 64), 256, 0, stream>>>(
        embed, HH, HH, nullptr, 0, 0, w_ih0, HH, b_ih0, P0, G3, VV, G3);

    // 3) GRU layer 0 (xp gathered from P0 by token id)
    gru_mfma<<<BB / 16, 512, 0, stream>>>(wT0, b_hh0, P0, x, h1, nullptr, 0);

    // 4) xp1 = h1 @ w_ih1.T + b_ih1   (8192 x 768, K=256)
    gemm_bt<<<dim3(G3 / 64, BB * TT / 64), 256, 0, stream>>>(
        h1, HH, HH, nullptr, 0, 0, w_ih1, HH, b_ih1, xp1, G3, BB * TT, G3);

    // 5) GRU layer 1 -> enc, h_last
    gru_mfma<<<BB / 16, 512, 0, stream>>>(wT1, b_hh1, xp1, nullptr, enc, hlast, 1);

    // 6) attention precomputes: Wa_e = enc @ W_a.T ; Ua_h = enc @ U_a.T
    gemm_bt<<<dim3(HH / 64, BB * TT / 64), 256, 0, stream>>>(
        enc, HH, HH, nullptr, 0, 0, W_a, HH, nullptr, Wae, HH, BB * TT, HH);
    gemm_bt<<<dim3(HH / 64, BB * TT / 64), 256, 0, stream>>>(
        enc, HH, HH, nullptr, 0, 0, U_a, HH, nullptr, Uah, HH, BB * TT, HH);

    // 7) attention: energy -> softmax -> ctx
    attn_kernel<<<dim3(TT, BB), 256, 0, stream>>>(Wae, Uah, enc, v_a, ctxb);

    // 8) logits = [enc | ctx] @ fc_W.T + fc_b  (split-A GEMM, K=256+256)
    gemm_bt<<<dim3(VV / 64, BB * TT / 64), 256, 0, stream>>>(
        enc, HH, HH, ctxb, HH, HH, fc_W, 2 * HH, fc_b, logits, VV, BB * TT, VV);
}

// Round 4
// 679.895 us; speedup vs baseline: 1.6539x; 1.3910x over previous
//
#include <hip/hip_runtime.h>
#include <math.h>

// Problem dims (AttentionRNN): B=128, T=64, H=256, V=128
#define BB 128
#define TT 64
#define HH 256
#define G3 768   // 3*H
#define VV 128

typedef _Float16 half8 __attribute__((ext_vector_type(8)));
typedef float f32x4 __attribute__((ext_vector_type(4)));

// ---------------------------------------------------------------------------
// Pack w_hh [768][256] f32 -> f16 MFMA B-fragments, in the exact per-lane
// order gru_mfma consumes: [wave 8][tile 6][ktile 8][lane 64][elem 8].
// Fragment def (v_mfma_f32_16x16x32_f16 B): col = lane&15, k = (lane>>4)*8+e.
// Tile tau: gate g = tau/2, sub s = tau&1 -> ncol = g*256 + wave*32 + s*16.
// ---------------------------------------------------------------------------
__global__ __launch_bounds__(256) void pack_whh_f16(const float* __restrict__ w,
                                                    _Float16* __restrict__ out) {
    int d = blockIdx.x * 256 + threadIdx.x;   // 196608 total
    int e   = d & 7;
    int l   = (d >> 3) & 63;
    int kap = (d >> 9) & 7;
    int wt  = d >> 12;                        // wave*6 + tau
    int wv  = wt / 6, tau = wt % 6;
    int ncol = (tau >> 1) * 256 + wv * 32 + (tau & 1) * 16 + (l & 15);
    int k    = kap * 32 + (l >> 4) * 8 + e;
    out[d] = (_Float16)w[ncol * HH + k];
}

// Folded bias: out[j] = b_ih[j] + (j<512 ? b_hh[j] : 0).  (r,z parts of b_hh
// ride along in xp; the n part must stay separate since it's scaled by r.)
__global__ __launch_bounds__(256) void prep_bias(const float* __restrict__ b_ih,
                                                 const float* __restrict__ b_hh,
                                                 float* __restrict__ outb) {
    int j = blockIdx.x * 256 + threadIdx.x;   // 768
    outb[j] = b_ih[j] + (j < 2 * HH ? b_hh[j] : 0.f);
}

// ---------------------------------------------------------------------------
// Generic f32 GEMM: C[M,N] = A[M,K1+K2] @ B[N,K1+K2]^T + bias
// Split-A so the logits GEMM reads concat(enc,ctx) without materializing it.
// 64x64 tile, BK=16, 256 threads, 4x4 per thread.
// ---------------------------------------------------------------------------
__global__ __launch_bounds__(256) void gemm_bt(
    const float* __restrict__ A1, int lda1, int K1,
    const float* __restrict__ A2, int lda2, int K2,
    const float* __restrict__ Bw, int ldb,
    const float* __restrict__ bias,
    float* __restrict__ C, int ldc, int M, int N)
{
    __shared__ alignas(16) float As[16][68];
    __shared__ alignas(16) float Bs[16][68];
    const int tid = threadIdx.x;
    const int lc = tid & 15, lr = tid >> 4;
    const int ty = tid >> 4, tx = tid & 15;
    const int row0 = blockIdx.y * 64, col0 = blockIdx.x * 64;
    float acc[4][4] = {};
    const int KT = K1 + K2;

    for (int k0 = 0; k0 < KT; k0 += 16) {
        const float* Ap; int lda, kk0;
        if (k0 < K1) { Ap = A1; lda = lda1; kk0 = k0; }
        else         { Ap = A2; lda = lda2; kk0 = k0 - K1; }
#pragma unroll
        for (int r = 0; r < 4; ++r) {
            As[lc][lr + 16 * r] = Ap[(row0 + lr + 16 * r) * lda + kk0 + lc];
            Bs[lc][lr + 16 * r] = Bw[(col0 + lr + 16 * r) * ldb + k0 + lc];
        }
        __syncthreads();
#pragma unroll
        for (int kk = 0; kk < 16; ++kk) {
            const float4 a4 = *(const float4*)&As[kk][ty * 4];
            const float4 b4 = *(const float4*)&Bs[kk][tx * 4];
            const float av[4] = {a4.x, a4.y, a4.z, a4.w};
            const float bv[4] = {b4.x, b4.y, b4.z, b4.w};
#pragma unroll
            for (int i = 0; i < 4; ++i)
#pragma unroll
                for (int j = 0; j < 4; ++j)
                    acc[i][j] += av[i] * bv[j];
        }
        __syncthreads();
    }

    float bv[4];
#pragma unroll
    for (int j = 0; j < 4; ++j)
        bv[j] = bias ? bias[col0 + tx * 4 + j] : 0.f;
#pragma unroll
    for (int i = 0; i < 4; ++i) {
        const int r = row0 + ty * 4 + i;
        float4 o;
        o.x = acc[i][0] + bv[0];
        o.y = acc[i][1] + bv[1];
        o.z = acc[i][2] + bv[2];
        o.w = acc[i][3] + bv[3];
        *(float4*)&C[r * ldc + col0 + tx * 4] = o;
    }
}

// ---------------------------------------------------------------------------
// MFMA GRU layer, register-resident weights.
// 8 blocks x 16 batch rows, 512 threads (8 waves), 1 block/CU.
// Prologue: each wave loads its 48 B-fragments (192 VGPR) ONCE.
// Per step: 8 ds_read A-frags -> 48 MFMA -> gates (xp loaded in-phase).
// b_hh r/z parts are pre-folded into xsrc's bias; only the n-part (bhn)
// is applied here (it is scaled by r before adding).
// ---------------------------------------------------------------------------
__global__ __launch_bounds__(512, 2) void gru_mfma(
    const _Float16* __restrict__ wp,  // packed fragments (see pack_whh_f16)
    const float* __restrict__ b_hh,   // [768]; only [512:768) used here
    const float* __restrict__ xsrc,   // P0 [128][768] (mode0) or xp1 [8192][768]
    const int*   __restrict__ xidx,   // token ids (mode0)
    float* __restrict__ out_seq,      // [B*T][256]
    float* __restrict__ hlast,        // [B][256] (mode1 only)
    int mode)
{
    __shared__ alignas(16) _Float16 hbuf[16][264];   // +8 pad
    __shared__ int tok[16][TT];                      // mode0 token ids
    const int tid = threadIdx.x;
    const int wv = tid >> 6, l = tid & 63;
    const int l15 = l & 15, lhi = l >> 4;
    const int r0 = blockIdx.x * 16;

    for (int i = tid; i < 16 * 264; i += 512) ((_Float16*)hbuf)[i] = (_Float16)0.f;
    if (mode == 0) {
        ((int*)tok)[tid]       = xidx[r0 * TT + tid];
        ((int*)tok)[tid + 512] = xidx[r0 * TT + tid + 512];
    }

    // ---- load all 48 weight fragments into registers (once) ----
    half8 W[48];
    const half8* wp8 = (const half8*)wp;
    const int fb = wv * 48 * 64;
#pragma unroll
    for (int f = 0; f < 48; ++f) W[f] = wp8[fb + f * 64 + l];

    const int colbase = wv * 32 + l15;
    const float bhn0 = b_hh[2 * HH + colbase];
    const float bhn1 = b_hh[2 * HH + colbase + 16];
    float hold[2][4] = {};
    __syncthreads();

    for (int t = 0; t < TT; ++t) {
        f32x4 acc[6];
#pragma unroll
        for (int tau = 0; tau < 6; ++tau) acc[tau] = (f32x4)0.f;

#pragma unroll
        for (int kap = 0; kap < 8; ++kap) {
            const half8 a = *(const half8*)&hbuf[l15][kap * 32 + lhi * 8];
#pragma unroll
            for (int tau = 0; tau < 6; ++tau)
                acc[tau] = __builtin_amdgcn_mfma_f32_16x16x32_f16(
                    a, W[tau * 8 + kap], acc[tau], 0, 0, 0);
        }
        __syncthreads();   // all waves' A-reads done before h is overwritten

        // gates: C-layout col = l&15, row = (l>>4)*4 + reg
#pragma unroll
        for (int s = 0; s < 2; ++s) {
            const int col = colbase + s * 16;
            const float bhn = s ? bhn1 : bhn0;
            float xr[4], xz[4], xn[4];
#pragma unroll
            for (int reg = 0; reg < 4; ++reg) {
                const int rr = lhi * 4 + reg;
                const long base = (mode == 0)
                    ? (long)tok[rr][t] * G3
                    : (long)((r0 + rr) * TT + t) * G3;
                xr[reg] = xsrc[base + col];
                xz[reg] = xsrc[base + col + HH];
                xn[reg] = xsrc[base + col + 2 * HH];
            }
#pragma unroll
            for (int reg = 0; reg < 4; ++reg) {
                const int row = lhi * 4 + reg;
                const float pr = acc[0 + s][reg] + xr[reg];
                const float pz = acc[2 + s][reg] + xz[reg];
                const float hn = acc[4 + s][reg] + bhn;
                const float rg = 1.f / (1.f + __expf(-pr));
                const float zg = 1.f / (1.f + __expf(-pz));
                const float npre = xn[reg] + rg * hn;
                const float e2 = __expf(2.f * npre);
                const float ng = (e2 - 1.f) / (e2 + 1.f);
                const float hnew = (1.f - zg) * ng + zg * hold[s][reg];
                hold[s][reg] = hnew;
                hbuf[row][col] = (_Float16)hnew;
                const int brow = r0 + row;
                out_seq[(brow * TT + t) * HH + col] = hnew;
                if (mode == 1 && t == TT - 1) hlast[brow * HH + col] = hnew;
            }
        }
        __syncthreads();
    }
}

// ---------------------------------------------------------------------------
// Bahdanau attention, one block per (b,t): energy -> softmax(k) -> ctx.
// WU holds [Wa_e | Ua_h] interleaved per row (stride 512).
// ---------------------------------------------------------------------------
__device__ __forceinline__ float tanh_fast(float x) {
    const float e = __expf(2.f * x);
    return (e - 1.f) / (e + 1.f);
}

__global__ __launch_bounds__(256) void attn_kernel(
    const float* __restrict__ WU,    // [B*T][512]: cols 0..255 Wa_e, 256..511 Ua_h
    const float* __restrict__ enc,   // [B*T][256]
    const float* __restrict__ v_a,   // [256]
    float* __restrict__ ctx)         // [B*T][256]
{
    __shared__ float q[HH], va[HH], sm[TT];
    const int tid = threadIdx.x;
    const int t = blockIdx.x, b = blockIdx.y;

    q[tid]  = WU[(b * TT + t) * 512 + 256 + tid];
    va[tid] = v_a[tid];
    __syncthreads();

    const int w = tid >> 6, lane = tid & 63;
#pragma unroll 4
    for (int i = 0; i < 16; ++i) {
        const int k = w * 16 + i;
        const float* we = WU + (b * TT + k) * 512;
        float s = 0.f;
#pragma unroll
        for (int c = 0; c < 4; ++c) {
            const int h = lane + 64 * c;
            s += va[h] * tanh_fast(we[h] + q[h]);
        }
#pragma unroll
        for (int off = 32; off > 0; off >>= 1) s += __shfl_xor(s, off);
        if (lane == 0) sm[k] = s;
    }
    __syncthreads();

    if (tid < TT) {
        const float e = sm[tid];
        float mx = e;
#pragma unroll
        for (int off = 32; off > 0; off >>= 1) mx = fmaxf(mx, __shfl_xor(mx, off));
        const float p = __expf(e - mx);
        float sum = p;
#pragma unroll
        for (int off = 32; off > 0; off >>= 1) sum += __shfl_xor(sum, off);
        sm[tid] = p / sum;
    }
    __syncthreads();

    float c = 0.f;
    for (int k = 0; k < TT; ++k)
        c += sm[k] * enc[(b * TT + k) * HH + tid];
    ctx[(b * TT + t) * HH + tid] = c;
}

// ---------------------------------------------------------------------------
extern "C" void kernel_launch(void* const* d_in, const int* in_sizes, int n_in,
                              void* d_out, int out_size, void* d_ws, size_t ws_size,
                              hipStream_t stream) {
    const int*   x     = (const int*)  d_in[0];
    const float* embed = (const float*)d_in[1];
    const float* w_ih0 = (const float*)d_in[2];
    const float* w_hh0 = (const float*)d_in[3];
    const float* b_ih0 = (const float*)d_in[4];
    const float* b_hh0 = (const float*)d_in[5];
    const float* w_ih1 = (const float*)d_in[6];
    const float* w_hh1 = (const float*)d_in[7];
    const float* b_ih1 = (const float*)d_in[8];
    const float* b_hh1 = (const float*)d_in[9];
    const float* W_a   = (const float*)d_in[10];
    const float* U_a   = (const float*)d_in[11];
    const float* v_a   = (const float*)d_in[12];
    const float* fc_W  = (const float*)d_in[13];
    const float* fc_b  = (const float*)d_in[14];
    float* out = (float*)d_out;

    // workspace layout (float words)
    float* ws = (float*)d_ws;
    _Float16* wT0 = (_Float16*)ws;        // 196608 f16 = 98304 floats
    _Float16* wT1 = wT0 + 196608;         // 196608 f16
    float* bias0 = ws    + 196608;        // 768
    float* bias1 = bias0 + 768;           // 768
    float* P0    = bias1 + 768;           // 98304
    float* h1    = P0    + 98304;         // 2097152
    float* xp1   = h1    + 2097152;       // 6291456
    float* enc   = xp1   + 6291456;       // 2097152
    float* WU_B  = enc   + 2097152;       // 131072  ([W_a;U_a] rows, ldb 256)
    float* WU    = WU_B  + 131072;        // 4194304 ([B*T][512])
    float* ctxb  = WU    + 4194304;       // 2097152

    float* logits = out;                  // [8192][128]
    float* hlast  = out + BB * TT * VV;   // [128][256]

    // 1) pack recurrent weights into f16 fragments; fold b_hh(r,z) into biases
    pack_whh_f16<<<768, 256, 0, stream>>>(w_hh0, wT0);
    pack_whh_f16<<<768, 256, 0, stream>>>(w_hh1, wT1);
    prep_bias<<<3, 256, 0, stream>>>(b_ih0, b_hh0, bias0);
    prep_bias<<<3, 256, 0, stream>>>(b_ih1, b_hh1, bias1);
    hipMemcpyAsync(WU_B, W_a, HH * HH * sizeof(float),
                   hipMemcpyDeviceToDevice, stream);
    hipMemcpyAsync(WU_B + HH * HH, U_a, HH * HH * sizeof(float),
                   hipMemcpyDeviceToDevice, stream);

    // 2) P0 = embed @ w_ih0.T + bias0   (128 x 768, K=256)
    gemm_bt<<<dim3(G3 / 64, VV / 64), 256, 0, stream>>>(
        embed, HH, HH, nullptr, 0, 0, w_ih0, HH, bias0, P0, G3, VV, G3);

    // 3) GRU layer 0 (xp gathered from P0 by token id)
    gru_mfma<<<BB / 16, 512, 0, stream>>>(wT0, b_hh0, P0, x, h1, nullptr, 0);

    // 4) xp1 = h1 @ w_ih1.T + bias1   (8192 x 768, K=256)
    gemm_bt<<<dim3(G3 / 64, BB * TT / 64), 256, 0, stream>>>(
        h1, HH, HH, nullptr, 0, 0, w_ih1, HH, bias1, xp1, G3, BB * TT, G3);

    // 5) GRU layer 1 -> enc, h_last
    gru_mfma<<<BB / 16, 512, 0, stream>>>(wT1, b_hh1, xp1, nullptr, enc, hlast, 1);

    // 6) WU = enc @ [W_a;U_a].T   (8192 x 512, K=256) — merged Wae/Uah
    gemm_bt<<<dim3(512 / 64, BB * TT / 64), 256, 0, stream>>>(
        enc, HH, HH, nullptr, 0, 0, WU_B, HH, nullptr, WU, 512, BB * TT, 512);

    // 7) attention: energy -> softmax -> ctx
    attn_kernel<<<dim3(TT, BB), 256, 0, stream>>>(WU, enc, v_a, ctxb);

    // 8) logits = [enc | ctx] @ fc_W.T + fc_b  (split-A GEMM, K=256+256)
    gemm_bt<<<dim3(VV / 64, BB * TT / 64), 256, 0, stream>>>(
        enc, HH, HH, ctxb, HH, HH, fc_W, 2 * HH, fc_b, logits, VV, BB * TT, VV);
}